// Round 5
// baseline (1557.073 us; speedup 1.0000x reference)
//
#include <hip/hip_runtime.h>
#include <hip/hip_bf16.h>
#include <math.h>

// Mean-shift as attention, fully fused: ONE persistent kernel, 1024 WGs
// (4/CU co-resident), device-scope atomic grid barriers between phases.
// Per iter: phase A (MFMA attention partials, round-4 body unchanged) ->
// barrier -> phase B (reduce+blend+regen kq/vv) -> barrier.

typedef short bf16x8 __attribute__((ext_vector_type(8)));
typedef float f32x16 __attribute__((ext_vector_type(16)));
typedef int v2i __attribute__((ext_vector_type(2)));

#define NPIX 8192
#define DIM 32
#define NITER 5
#define SCH 16                // i-chunks
#define CHUNK (NPIX / SCH)    // 512 i per WG
#define HALF 128              // i per LDS stage
#define HALVES (CHUNK / HALF) // 4
#define WAVES 4
#define PSTR 36
#define ALPHA 0.8493219f      // sqrt(0.5 * log2(e))
#define NWG 1024
#define NBAR 10
#define BARSTRIDE 80          // 64 group counters + root @64, padded

#if __has_builtin(__builtin_amdgcn_exp2f)
#define EXP2(x) __builtin_amdgcn_exp2f(x)
#else
#define EXP2(x) exp2f(x)
#endif

__device__ __forceinline__ void glds16(const uint4* g, uint4* l) {
#if __has_builtin(__builtin_amdgcn_global_load_lds)
    __builtin_amdgcn_global_load_lds((const __attribute__((address_space(1))) void*)g,
                                     (__attribute__((address_space(3))) void*)l,
                                     16, 0, 0);
#else
    *l = *g;
#endif
}

__device__ inline unsigned cvtpk(float lo, float hi) {
    unsigned r;
    asm("v_cvt_pk_bf16_f32 %0, %1, %2" : "=v"(r) : "v"(lo), "v"(hi));
    return r;
}

__device__ inline void swap32(unsigned a, unsigned b, unsigned& x, unsigned& y) {
#if __has_builtin(__builtin_amdgcn_permlane32_swap)
    v2i r = __builtin_amdgcn_permlane32_swap((int)a, (int)b, false, false);
    x = (unsigned)r.x;
    y = (unsigned)r.y;
#else
    unsigned bs = __shfl_xor(b, 32);
    unsigned as = __shfl_xor(a, 32);
    int hi = (int)(threadIdx.x & 63) >> 5;
    x = hi ? bs : a;
    y = hi ? b : as;
#endif
}

__device__ inline unsigned short f2bf(float f) {  // RNE
    unsigned u = __float_as_uint(f);
    unsigned r = (u + 0x7FFFu + ((u >> 16) & 1u)) >> 16;
    return (unsigned short)r;
}

__device__ inline unsigned pk2(float a, float b) {
    return (unsigned)f2bf(a) | ((unsigned)f2bf(b) << 16);
}

union U4 { uint4 q; bf16x8 v; };

// ---- two-level grid barrier (device-scope, one-shot counters per slot) ----
__device__ __forceinline__ void gridbar(unsigned* bar, int slot) {
    __syncthreads();
    if (threadIdx.x == 0) {
        unsigned* grp = bar + slot * BARSTRIDE + (blockIdx.x >> 4);
        unsigned* root = bar + slot * BARSTRIDE + 64;
        __threadfence();   // release my WG's prior stores
        unsigned prev = atomicAdd(grp, 1u);
        if (prev == 15u) atomicAdd(root, 1u);
        int guard = 0;
        while (__hip_atomic_load(root, __ATOMIC_ACQUIRE, __HIP_MEMORY_SCOPE_AGENT) < 64u) {
            __builtin_amdgcn_s_sleep(2);
            if (++guard > (1 << 22)) break;   // deadlock escape; never in healthy runs
        }
    }
    __syncthreads();
    __threadfence();       // acquire: invalidate stale cached lines for all threads
}

// ---- regenerate kq (scaled) + vv (raw) for the 8 j's whose xn sit in sxn[8][32] ----
__device__ __forceinline__ void regen(const float* sxn, int j0, int tid,
                                      unsigned short* kq, unsigned short* vv) {
    if (tid < 32) {
        int jl2 = tid >> 2, f = tid & 3;
        int j = j0 + jl2;
        const float* s = sxn + jl2 * 32 + f * 8;
        unsigned w0 = pk2(s[0] * ALPHA, s[1] * ALPHA);
        unsigned w1 = pk2(s[2] * ALPHA, s[3] * ALPHA);
        unsigned w2 = pk2(s[4] * ALPHA, s[5] * ALPHA);
        unsigned w3 = pk2(s[6] * ALPHA, s[7] * ALPHA);
        ((uint4*)kq)[(j >> 5) * 128 + (f >> 1) * 64 + (f & 1) * 32 + (j & 31)] =
            make_uint4(w0, w1, w2, w3);
    }
    int jl = tid >> 5, d = tid & 31;
    int j = j0 + jl;
    int vbase = (j >> 5) * 1024 + ((j >> 4) & 1) * 512 + ((j >> 3) & 1) * 256 + (j & 7);
    vv[vbase + d * 8] = f2bf(sxn[jl * 32 + d]);
}

// ---- phase A: attention partials for (jgroup = wg>>4, chunk = wg&15) ----
__device__ __forceinline__ void phaseA(const unsigned short* kq, const unsigned short* vv,
                                       float* part, int tid, int wg, uint4* sm) {
    const int lane = tid & 63;
    const int lo = lane & 31, hi = lane >> 5;
    const int wv = tid >> 6;
    const int wbase = tid & ~63;
    const int jblk = (wg >> 4) * WAVES + wv;   // 0..255
    const int chunk = wg & 15;                 // 0..15

    const uint4* kq4 = (const uint4*)kq;
    const uint4* vv4 = (const uint4*)vv;

    U4 q0, q1;
    q0.q = kq4[jblk * 128 + lane];
    q1.q = kq4[jblk * 128 + 64 + lane];

    U4 ones;
    ones.q = make_uint4(0x3F803F80u, 0x3F803F80u, 0x3F803F80u, 0x3F803F80u);

    f32x16 z16;
#pragma unroll
    for (int r = 0; r < 16; ++r) z16[r] = 0.f;
    f32x16 y = z16;
    f32x16 dg16 = z16;

    const uint4* gk = kq4 + (size_t)chunk * CHUNK * 4;
    const uint4* gv = vv4 + (size_t)chunk * CHUNK * 4;

    auto STAGE = [&](int h, int b) {
        const uint4* gkh = gk + h * (HALF * 4);
        const uint4* gvh = gv + h * (HALF * 4);
        uint4* dK = sm + b * 1024 + wbase;
        uint4* dV = dK + 512;
#pragma unroll
        for (int r = 0; r < 2; ++r) {
            glds16(gkh + r * 256 + tid, dK + r * 256);
            glds16(gvh + r * 256 + tid, dV + r * 256);
        }
    };

    STAGE(0, 0);

    for (int h = 0; h < HALVES; ++h) {
        __builtin_amdgcn_s_barrier();
        if (h + 1 < HALVES) {
            STAGE(h + 1, (h + 1) & 1);
            asm volatile("s_waitcnt vmcnt(4)" ::: "memory");
        } else {
            asm volatile("s_waitcnt vmcnt(0)" ::: "memory");
        }
        __builtin_amdgcn_s_barrier();

        const uint4* bK = sm + ((h & 1) << 10);
        const uint4* bV = bK + 512;
#pragma unroll
        for (int it = 0; it < HALF / 32; ++it) {
            U4 ka0, ka1, vb0, vb1;
            ka0.q = bK[it * 128 + lane];
            ka1.q = bK[it * 128 + 64 + lane];
            vb0.q = bV[it * 128 + lane];
            vb1.q = bV[it * 128 + 64 + lane];

            f32x16 s;
            s = __builtin_amdgcn_mfma_f32_32x32x16_bf16(ka0.v, q0.v, z16, 0, 0, 0);
            s = __builtin_amdgcn_mfma_f32_32x32x16_bf16(ka1.v, q1.v, s, 0, 0, 0);
            float p[16];
#pragma unroll
            for (int r = 0; r < 16; ++r) p[r] = EXP2(s[r]);

#pragma unroll
            for (int ks = 0; ks < 2; ++ks) {
                const float* pb = p + ks * 8;
                unsigned a0 = cvtpk(pb[0], pb[1]);
                unsigned a1 = cvtpk(pb[2], pb[3]);
                unsigned b0 = cvtpk(pb[4], pb[5]);
                unsigned b1 = cvtpk(pb[6], pb[7]);
                unsigned w01, w45, w23, w67;
                swap32(a0, b0, w01, w45);
                swap32(a1, b1, w23, w67);
                U4 pa;
                pa.q = make_uint4(w01, w23, w45, w67);
                y = __builtin_amdgcn_mfma_f32_32x32x16_bf16(
                        pa.v, (ks ? vb1.v : vb0.v), y, 0, 0, 0);
                dg16 = __builtin_amdgcn_mfma_f32_32x32x16_bf16(
                        pa.v, ones.v, dg16, 0, 0, 0);
            }
        }
    }

    float* prow = part + ((size_t)chunk * NPIX + (size_t)jblk * 32) * PSTR;
#pragma unroll
    for (int r = 0; r < 16; ++r) {
        int jr = (r & 3) + 8 * (r >> 2) + 4 * hi;
        prow[(size_t)jr * PSTR + lo] = y[r];
        if (lo == 0) prow[(size_t)jr * PSTR + 32] = dg16[r];
    }
}

// ---------------- fused kernel ----------------
__global__ __launch_bounds__(256, 4) void k_fused(const float* __restrict__ xin,
                                                  float* xmA, float* xmB,
                                                  float* part,
                                                  unsigned short* kq,
                                                  unsigned short* vv,
                                                  float* __restrict__ out,
                                                  unsigned* bar) {
    __shared__ uint4 sm[2048];   // 32 KB: phase-A staging; phase-B sxn reuse
    float* sf = (float*)sm;
    const int tid = threadIdx.x;
    const int wg = blockIdx.x;
    const int j0 = wg * 8;

    // ---- prep: x_in [32][8192] -> xmA [j][32], kq, vv ----
    {
        int dd = tid >> 3, jl8 = tid & 7;
        float v = xin[(size_t)dd * NPIX + j0 + jl8];
        sf[jl8 * 32 + dd] = v;
        __syncthreads();
        int jl = tid >> 5, d = tid & 31;
        xmA[(size_t)(j0 + jl) * 32 + d] = sf[jl * 32 + d];
        regen(sf, j0, tid, kq, vv);
    }
    gridbar(bar, 0);

    float* xmr = xmA;
    float* xmw = xmB;
    for (int itr = 0; itr < NITER; ++itr) {
        phaseA(kq, vv, part, tid, wg, sm);
        gridbar(bar, 1 + 2 * itr);

        // ---- phase B: reduce + blend (+ regen) for 8 j's ----
        int jl = tid >> 5, d = tid & 31;
        int j = j0 + jl;
        float ys = 0.f, dg = 0.f;
        for (int c = 0; c < SCH; ++c) {
            const float* pr = part + ((size_t)c * NPIX + j) * PSTR;
            ys += pr[d];
            dg += pr[32];
        }
        float xn = fmaf(ys, 0.5f / dg, 0.5f * xmr[(size_t)j * 32 + d]);

        if (itr == NITER - 1) {
            out[(size_t)d * NPIX + j] = xn;
        } else {
            xmw[(size_t)j * 32 + d] = xn;
            sf[jl * 32 + d] = xn;
            __syncthreads();
            regen(sf, j0, tid, kq, vv);
            gridbar(bar, 2 + 2 * itr);
            float* t = xmr; xmr = xmw; xmw = t;
        }
    }
}

extern "C" void kernel_launch(void* const* d_in, const int* in_sizes, int n_in,
                              void* d_out, int out_size, void* d_ws, size_t ws_size,
                              hipStream_t stream) {
    const float* x_in = (const float*)d_in[0];
    float* out = (float*)d_out;

    const size_t nd = (size_t)NPIX * DIM;          // 262144
    float* xmA = (float*)d_ws;
    float* xmB = xmA + nd;
    float* part = xmB + nd;                        // SCH*8192*36 floats
    unsigned short* kq = (unsigned short*)(part + (size_t)SCH * NPIX * PSTR);
    unsigned short* vv = kq + nd;
    unsigned* bar = (unsigned*)(vv + nd);

    hipMemsetAsync(bar, 0, NBAR * BARSTRIDE * sizeof(unsigned), stream);
    k_fused<<<NWG, 256, 0, stream>>>(x_in, xmA, xmB, part, kq, vv, out, bar);
}

// Round 6
// 572.337 us; speedup vs baseline: 2.7206x; 2.7206x over previous
//
#include <hip/hip_runtime.h>
#include <hip/hip_bf16.h>
#include <math.h>

// Mean-shift as attention. Round 6 = round-4 structure (grid-barrier fusion
// reverted: device-scope fences cost ~150us/barrier on non-coherent XCD L2s).
// Change: 8 waves/SIMD (SCH=32, HALF=64 -> 16KB LDS, __launch_bounds__(256,8);
// phase-A body measured at 64 VGPR in round 5, so the cap is free).
// K and Q scaled by ALPHA=sqrt(0.5*log2 e): inner loop is exp2 only.
// Swapped QK^T (mfma(K,Q)) keeps P lane-local; cvt_pk+permlane32_swap builds
// the PV A-fragment; deg rides MFMA with all-ones B. Operand arrays are
// pre-permuted fragment-order so staging is linear and reads conflict-free.

typedef short bf16x8 __attribute__((ext_vector_type(8)));
typedef float f32x16 __attribute__((ext_vector_type(16)));
typedef int v2i __attribute__((ext_vector_type(2)));

#define NPIX 8192
#define DIM 32
#define NITER 5
#define SCH 32                // i-chunks (grid.y)
#define CHUNK (NPIX / SCH)    // 256 i per WG
#define HALF 64               // i per LDS stage
#define HALVES (CHUNK / HALF) // 4
#define WAVES 4               // waves per WG (128 j per WG)
#define PSTR 36               // partial row stride (32 y + deg + pad)
#define ALPHA 0.8493219f      // sqrt(0.5 * log2(e))

#if __has_builtin(__builtin_amdgcn_exp2f)
#define EXP2(x) __builtin_amdgcn_exp2f(x)
#else
#define EXP2(x) exp2f(x)
#endif

#if __has_builtin(__builtin_amdgcn_global_load_lds)
#define HAS_GLDS 1
#else
#define HAS_GLDS 0
#endif

__device__ __forceinline__ void glds16(const uint4* g, uint4* l) {
#if HAS_GLDS
    __builtin_amdgcn_global_load_lds((const __attribute__((address_space(1))) void*)g,
                                     (__attribute__((address_space(3))) void*)l,
                                     16, 0, 0);
#else
    *l = *g;
#endif
}

__device__ inline unsigned cvtpk(float lo, float hi) {
    unsigned r;
    asm("v_cvt_pk_bf16_f32 %0, %1, %2" : "=v"(r) : "v"(lo), "v"(hi));
    return r;
}

__device__ inline void swap32(unsigned a, unsigned b, unsigned& x, unsigned& y) {
#if __has_builtin(__builtin_amdgcn_permlane32_swap)
    v2i r = __builtin_amdgcn_permlane32_swap((int)a, (int)b, false, false);
    x = (unsigned)r.x;
    y = (unsigned)r.y;
#else
    unsigned bs = __shfl_xor(b, 32);
    unsigned as = __shfl_xor(a, 32);
    int hi = (int)(threadIdx.x & 63) >> 5;
    x = hi ? bs : a;
    y = hi ? b : as;
#endif
}

__device__ inline unsigned short f2bf(float f) {  // RNE
    unsigned u = __float_as_uint(f);
    unsigned r = (u + 0x7FFFu + ((u >> 16) & 1u)) >> 16;
    return (unsigned short)r;
}

union U4 { uint4 q; bf16x8 v; };

// ---------------- main pair kernel ----------------
__global__ __launch_bounds__(256, 8) void k_ms(const unsigned short* __restrict__ kq,
                                               const unsigned short* __restrict__ vv,
                                               float* __restrict__ part) {
    __shared__ uint4 sm[1024];  // 2 bufs x (K 256 | V 256) uint4 = 16 KB
    const int tid = threadIdx.x;
    const int lane = tid & 63;
    const int lo = lane & 31, hi = lane >> 5;
    const int wv = tid >> 6;
    const int wbase = tid & ~63;
    const int jblk = blockIdx.x * WAVES + wv;   // 0..255
    const int chunk = blockIdx.y;               // 0..SCH-1

    const uint4* kq4 = (const uint4*)kq;
    const uint4* vv4 = (const uint4*)vv;

    // Q fragments (B-operand): lane holds col j, k-elems d = ks*16 + hi*8 + e
    U4 q0, q1;
    q0.q = kq4[jblk * 128 + lane];
    q1.q = kq4[jblk * 128 + 64 + lane];

    U4 ones;
    ones.q = make_uint4(0x3F803F80u, 0x3F803F80u, 0x3F803F80u, 0x3F803F80u);

    f32x16 z16;
#pragma unroll
    for (int r = 0; r < 16; ++r) z16[r] = 0.f;
    f32x16 y = z16;
    f32x16 dg16 = z16;

    const uint4* gk = kq4 + (size_t)chunk * CHUNK * 4;   // 64 B per i
    const uint4* gv = vv4 + (size_t)chunk * CHUNK * 4;

    auto STAGE = [&](int h, int b) {
        const uint4* gkh = gk + h * (HALF * 4);
        const uint4* gvh = gv + h * (HALF * 4);
        uint4* dK = sm + b * 512 + wbase;   // wave-uniform LDS base
        uint4* dV = dK + 256;
        glds16(gkh + tid, dK);
        glds16(gvh + tid, dV);
    };

    STAGE(0, 0);

    for (int h = 0; h < HALVES; ++h) {
        __builtin_amdgcn_s_barrier();            // prev compute done
        if (h + 1 < HALVES) {
            STAGE(h + 1, (h + 1) & 1);
            asm volatile("s_waitcnt vmcnt(2)" ::: "memory");  // buf[h] landed (mine)
        } else {
            asm volatile("s_waitcnt vmcnt(0)" ::: "memory");
        }
        __builtin_amdgcn_s_barrier();            // buf[h] landed (everyone)

        const uint4* bK = sm + ((h & 1) << 9);
        const uint4* bV = bK + 256;
#pragma unroll
        for (int it = 0; it < HALF / 32; ++it) {
            U4 ka0, ka1, vb0, vb1;
            ka0.q = bK[it * 128 + lane];
            ka1.q = bK[it * 128 + 64 + lane];
            vb0.q = bV[it * 128 + lane];
            vb1.q = bV[it * 128 + 64 + lane];

            f32x16 s;
            s = __builtin_amdgcn_mfma_f32_32x32x16_bf16(ka0.v, q0.v, z16, 0, 0, 0);
            s = __builtin_amdgcn_mfma_f32_32x32x16_bf16(ka1.v, q1.v, s, 0, 0, 0);
            // lane holds P[i = crow(r,hi), j = lo]
            float p[16];
#pragma unroll
            for (int r = 0; r < 16; ++r) p[r] = EXP2(s[r]);

#pragma unroll
            for (int ks = 0; ks < 2; ++ks) {
                const float* pb = p + ks * 8;
                unsigned a0 = cvtpk(pb[0], pb[1]);
                unsigned a1 = cvtpk(pb[2], pb[3]);
                unsigned b0 = cvtpk(pb[4], pb[5]);
                unsigned b1 = cvtpk(pb[6], pb[7]);
                unsigned w01, w45, w23, w67;
                swap32(a0, b0, w01, w45);
                swap32(a1, b1, w23, w67);
                U4 pa;
                pa.q = make_uint4(w01, w23, w45, w67);
                y = __builtin_amdgcn_mfma_f32_32x32x16_bf16(
                        pa.v, (ks ? vb1.v : vb0.v), y, 0, 0, 0);
                dg16 = __builtin_amdgcn_mfma_f32_32x32x16_bf16(
                        pa.v, ones.v, dg16, 0, 0, 0);
            }
        }
    }

    float* prow = part + ((size_t)chunk * NPIX + (size_t)jblk * 32) * PSTR;
#pragma unroll
    for (int r = 0; r < 16; ++r) {
        int jr = (r & 3) + 8 * (r >> 2) + 4 * hi;
        prow[(size_t)jr * PSTR + lo] = y[r];
        if (lo == 0) prow[(size_t)jr * PSTR + 32] = dg16[r];
    }
}

// ---------------- prep: x_in [32][8192] -> master [j][32] + permuted bf16 ----------------
__global__ __launch_bounds__(256) void k_prep(const float* __restrict__ xin,
                                              float* __restrict__ xm,
                                              unsigned short* __restrict__ kq,
                                              unsigned short* __restrict__ vv) {
    const int j = blockIdx.x * 256 + threadIdx.x;
    float xv[DIM];
#pragma unroll
    for (int d = 0; d < DIM; ++d) xv[d] = xin[(size_t)d * NPIX + j];

    float4* xmr = (float4*)(xm + (size_t)j * DIM);
#pragma unroll
    for (int q = 0; q < 8; ++q)
        xmr[q] = make_float4(xv[4*q], xv[4*q+1], xv[4*q+2], xv[4*q+3]);

    uint4* kq4 = (uint4*)kq;
#pragma unroll
    for (int ks = 0; ks < 2; ++ks)
#pragma unroll
        for (int h = 0; h < 2; ++h) {
            const int b = ks * 16 + h * 8;
            unsigned w0 = (unsigned)f2bf(xv[b+0]*ALPHA) | ((unsigned)f2bf(xv[b+1]*ALPHA) << 16);
            unsigned w1 = (unsigned)f2bf(xv[b+2]*ALPHA) | ((unsigned)f2bf(xv[b+3]*ALPHA) << 16);
            unsigned w2 = (unsigned)f2bf(xv[b+4]*ALPHA) | ((unsigned)f2bf(xv[b+5]*ALPHA) << 16);
            unsigned w3 = (unsigned)f2bf(xv[b+6]*ALPHA) | ((unsigned)f2bf(xv[b+7]*ALPHA) << 16);
            kq4[(j >> 5) * 128 + ks * 64 + h * 32 + (j & 31)] = make_uint4(w0, w1, w2, w3);
        }

    const int vbase = (j >> 5) * 1024 + ((j >> 4) & 1) * 512 + ((j >> 3) & 1) * 256 + (j & 7);
#pragma unroll
    for (int d = 0; d < DIM; ++d) vv[vbase + d * 8] = f2bf(xv[d]);
}

// ---------------- reduce + blend + regenerate, 4 threads per j ----------------
__global__ __launch_bounds__(256) void k_upd(const float* __restrict__ part,
                                             const float* __restrict__ xm,
                                             float* __restrict__ xm_next,
                                             unsigned short* __restrict__ kq,
                                             unsigned short* __restrict__ vv,
                                             float* __restrict__ out,
                                             int last) {
    const int t = blockIdx.x * 256 + threadIdx.x;   // 0..32767
    const int j = t >> 2, q = t & 3;                // q: which 8-dim slice

    float4 ya = make_float4(0.f, 0.f, 0.f, 0.f);
    float4 yb = make_float4(0.f, 0.f, 0.f, 0.f);
    float dg = 0.f;
    for (int c = 0; c < SCH; ++c) {
        const float* pr = part + ((size_t)c * NPIX + j) * PSTR;
        const float4* p4 = (const float4*)(pr + q * 8);
        float4 a = p4[0], b = p4[1];
        ya.x += a.x; ya.y += a.y; ya.z += a.z; ya.w += a.w;
        yb.x += b.x; yb.y += b.y; yb.z += b.z; yb.w += b.w;
        dg += pr[32];                                // all 4 threads read same addr
    }
    const float inv = 0.5f / dg;

    const float4* xr = (const float4*)(xm + (size_t)j * DIM + q * 8);
    float4 v0 = xr[0], v1 = xr[1];
    float xn[8];
    xn[0] = fmaf(ya.x, inv, 0.5f * v0.x);
    xn[1] = fmaf(ya.y, inv, 0.5f * v0.y);
    xn[2] = fmaf(ya.z, inv, 0.5f * v0.z);
    xn[3] = fmaf(ya.w, inv, 0.5f * v0.w);
    xn[4] = fmaf(yb.x, inv, 0.5f * v1.x);
    xn[5] = fmaf(yb.y, inv, 0.5f * v1.y);
    xn[6] = fmaf(yb.z, inv, 0.5f * v1.z);
    xn[7] = fmaf(yb.w, inv, 0.5f * v1.w);

    if (last) {
#pragma unroll
        for (int e = 0; e < 8; ++e) out[(size_t)(q * 8 + e) * NPIX + j] = xn[e];
        return;
    }

    float4* xw = (float4*)(xm_next + (size_t)j * DIM + q * 8);
    xw[0] = make_float4(xn[0], xn[1], xn[2], xn[3]);
    xw[1] = make_float4(xn[4], xn[5], xn[6], xn[7]);

    unsigned w0 = (unsigned)f2bf(xn[0]*ALPHA) | ((unsigned)f2bf(xn[1]*ALPHA) << 16);
    unsigned w1 = (unsigned)f2bf(xn[2]*ALPHA) | ((unsigned)f2bf(xn[3]*ALPHA) << 16);
    unsigned w2 = (unsigned)f2bf(xn[4]*ALPHA) | ((unsigned)f2bf(xn[5]*ALPHA) << 16);
    unsigned w3 = (unsigned)f2bf(xn[6]*ALPHA) | ((unsigned)f2bf(xn[7]*ALPHA) << 16);
    ((uint4*)kq)[(j >> 5) * 128 + (q >> 1) * 64 + (q & 1) * 32 + (j & 31)] =
        make_uint4(w0, w1, w2, w3);

    const int vbase = (j >> 5) * 1024 + ((j >> 4) & 1) * 512 + ((j >> 3) & 1) * 256 + (j & 7);
#pragma unroll
    for (int e = 0; e < 8; ++e) vv[vbase + (q * 8 + e) * 8] = f2bf(xn[e]);
}

extern "C" void kernel_launch(void* const* d_in, const int* in_sizes, int n_in,
                              void* d_out, int out_size, void* d_ws, size_t ws_size,
                              hipStream_t stream) {
    const float* x_in = (const float*)d_in[0];
    float* out = (float*)d_out;

    const size_t nd = (size_t)NPIX * DIM;          // 262144
    float* xmA = (float*)d_ws;
    float* xmB = xmA + nd;
    float* part = xmB + nd;                        // SCH*8192*36 floats
    unsigned short* kq = (unsigned short*)(part + (size_t)SCH * NPIX * PSTR);
    unsigned short* vv = kq + nd;

    k_prep<<<NPIX / 256, 256, 0, stream>>>(x_in, xmA, kq, vv);

    for (int it = 0; it < NITER; ++it) {
        const int last = (it == NITER - 1);
        k_ms<<<dim3(NPIX / (32 * WAVES), SCH), 256, 0, stream>>>(kq, vv, part);
        k_upd<<<(NPIX * 4) / 256, 256, 0, stream>>>(part, xmA, xmB, kq, vv, out, last);
        float* t = xmA; xmA = xmB; xmB = t;
    }
}

// Round 7
// 134.848 us; speedup vs baseline: 11.5469x; 4.2443x over previous
//
#include <hip/hip_runtime.h>
#include <hip/hip_bf16.h>
#include <math.h>

// Mean-shift as attention. Round 7 = round-4 structure (4 WGs/CU, 32KB LDS,
// launch_bounds(256,4): round-6's (256,8) forced 32 arch VGPRs -> scratch
// spills, 353MB writes). New this round:
//  - dense partial layout: y [chunk][j][32] (full 128B lines), deg [chunk][j]
//  - XCD-chunk affinity: chunk = f(wg%8) so each chunk's K/V stays in one
//    XCD's L2 (round-6 FETCH showed zero cross-WG reuse: 64MB vs 2MB unique)

typedef short bf16x8 __attribute__((ext_vector_type(8)));
typedef float f32x16 __attribute__((ext_vector_type(16)));
typedef int v2i __attribute__((ext_vector_type(2)));

#define NPIX 8192
#define DIM 32
#define NITER 5
#define SCH 16                // i-chunks; 2 per XCD
#define CHUNK (NPIX / SCH)    // 512 i per WG
#define HALF 128              // i per LDS stage
#define HALVES (CHUNK / HALF) // 4
#define WAVES 4               // waves per WG (128 j per WG)
#define ALPHA 0.8493219f      // sqrt(0.5 * log2(e))

#if __has_builtin(__builtin_amdgcn_exp2f)
#define EXP2(x) __builtin_amdgcn_exp2f(x)
#else
#define EXP2(x) exp2f(x)
#endif

__device__ __forceinline__ void glds16(const uint4* g, uint4* l) {
#if __has_builtin(__builtin_amdgcn_global_load_lds)
    __builtin_amdgcn_global_load_lds((const __attribute__((address_space(1))) void*)g,
                                     (__attribute__((address_space(3))) void*)l,
                                     16, 0, 0);
#else
    *l = *g;
#endif
}

__device__ inline unsigned cvtpk(float lo, float hi) {
    unsigned r;
    asm("v_cvt_pk_bf16_f32 %0, %1, %2" : "=v"(r) : "v"(lo), "v"(hi));
    return r;
}

__device__ inline void swap32(unsigned a, unsigned b, unsigned& x, unsigned& y) {
#if __has_builtin(__builtin_amdgcn_permlane32_swap)
    v2i r = __builtin_amdgcn_permlane32_swap((int)a, (int)b, false, false);
    x = (unsigned)r.x;
    y = (unsigned)r.y;
#else
    unsigned bs = __shfl_xor(b, 32);
    unsigned as = __shfl_xor(a, 32);
    int hi = (int)(threadIdx.x & 63) >> 5;
    x = hi ? bs : a;
    y = hi ? b : as;
#endif
}

__device__ inline unsigned short f2bf(float f) {  // RNE
    unsigned u = __float_as_uint(f);
    unsigned r = (u + 0x7FFFu + ((u >> 16) & 1u)) >> 16;
    return (unsigned short)r;
}

union U4 { uint4 q; bf16x8 v; };

// ---------------- main pair kernel ----------------
__global__ __launch_bounds__(256, 4) void k_ms(const unsigned short* __restrict__ kq,
                                               const unsigned short* __restrict__ vv,
                                               float* __restrict__ party,
                                               float* __restrict__ partd) {
    __shared__ uint4 sm[2048];  // 2 bufs x (K 512 | V 512) uint4 = 32 KB
    const int tid = threadIdx.x;
    const int lane = tid & 63;
    const int lo = lane & 31, hi = lane >> 5;
    const int wv = tid >> 6;
    const int wbase = tid & ~63;

    // XCD-affine decode: consecutive blockIdx round-robin across 8 XCDs,
    // so chunk = xcd*2 + bit keeps each chunk's K/V in one XCD's L2.
    const int wg = blockIdx.x;                  // 0..1023
    const int xcd = wg & 7;
    const int idx = wg >> 3;                    // 0..127
    const int chunk = xcd * 2 + (idx >> 6);     // 0..15
    const int jblk = (idx & 63) * WAVES + wv;   // 0..255

    const uint4* kq4 = (const uint4*)kq;
    const uint4* vv4 = (const uint4*)vv;

    // Q fragments (B-operand): lane holds col j, k-elems d = ks*16 + hi*8 + e
    U4 q0, q1;
    q0.q = kq4[jblk * 128 + lane];
    q1.q = kq4[jblk * 128 + 64 + lane];

    U4 ones;
    ones.q = make_uint4(0x3F803F80u, 0x3F803F80u, 0x3F803F80u, 0x3F803F80u);

    f32x16 z16;
#pragma unroll
    for (int r = 0; r < 16; ++r) z16[r] = 0.f;
    f32x16 y = z16;
    f32x16 dg16 = z16;

    const uint4* gk = kq4 + (size_t)chunk * CHUNK * 4;   // 64 B per i
    const uint4* gv = vv4 + (size_t)chunk * CHUNK * 4;

    auto STAGE = [&](int h, int b) {
        const uint4* gkh = gk + h * (HALF * 4);
        const uint4* gvh = gv + h * (HALF * 4);
        uint4* dK = sm + b * 1024 + wbase;   // wave-uniform LDS base
        uint4* dV = dK + 512;
#pragma unroll
        for (int r = 0; r < 2; ++r) {
            glds16(gkh + r * 256 + tid, dK + r * 256);
            glds16(gvh + r * 256 + tid, dV + r * 256);
        }
    };

    STAGE(0, 0);

    for (int h = 0; h < HALVES; ++h) {
        __builtin_amdgcn_s_barrier();            // prev compute done
        if (h + 1 < HALVES) {
            STAGE(h + 1, (h + 1) & 1);
            asm volatile("s_waitcnt vmcnt(4)" ::: "memory");  // buf[h] landed (mine)
        } else {
            asm volatile("s_waitcnt vmcnt(0)" ::: "memory");
        }
        __builtin_amdgcn_s_barrier();            // buf[h] landed (everyone)

        const uint4* bK = sm + ((h & 1) << 10);
        const uint4* bV = bK + 512;
#pragma unroll
        for (int it = 0; it < HALF / 32; ++it) {
            U4 ka0, ka1, vb0, vb1;
            ka0.q = bK[it * 128 + lane];
            ka1.q = bK[it * 128 + 64 + lane];
            vb0.q = bV[it * 128 + lane];
            vb1.q = bV[it * 128 + 64 + lane];

            f32x16 s;
            s = __builtin_amdgcn_mfma_f32_32x32x16_bf16(ka0.v, q0.v, z16, 0, 0, 0);
            s = __builtin_amdgcn_mfma_f32_32x32x16_bf16(ka1.v, q1.v, s, 0, 0, 0);
            // lane holds P[i = crow(r,hi), j = lo]
            float p[16];
#pragma unroll
            for (int r = 0; r < 16; ++r) p[r] = EXP2(s[r]);

#pragma unroll
            for (int ks = 0; ks < 2; ++ks) {
                const float* pb = p + ks * 8;
                unsigned a0 = cvtpk(pb[0], pb[1]);
                unsigned a1 = cvtpk(pb[2], pb[3]);
                unsigned b0 = cvtpk(pb[4], pb[5]);
                unsigned b1 = cvtpk(pb[6], pb[7]);
                unsigned w01, w45, w23, w67;
                swap32(a0, b0, w01, w45);
                swap32(a1, b1, w23, w67);
                U4 pa;
                pa.q = make_uint4(w01, w23, w45, w67);
                y = __builtin_amdgcn_mfma_f32_32x32x16_bf16(
                        pa.v, (ks ? vb1.v : vb0.v), y, 0, 0, 0);
                dg16 = __builtin_amdgcn_mfma_f32_32x32x16_bf16(
                        pa.v, ones.v, dg16, 0, 0, 0);
            }
        }
    }

    // dense stores: y rows are 128B-aligned full cachelines; deg separate
    float* yrow = party + ((size_t)chunk * NPIX + (size_t)jblk * 32) * 32;
    float* drow = partd + (size_t)chunk * NPIX + (size_t)jblk * 32;
#pragma unroll
    for (int r = 0; r < 16; ++r) {
        int jr = (r & 3) + 8 * (r >> 2) + 4 * hi;   // j within block
        yrow[(size_t)jr * 32 + lo] = y[r];          // lo = d
        if (lo == 0) drow[jr] = dg16[r];
    }
}

// ---------------- prep: x_in [32][8192] -> master [j][32] + permuted bf16 ----------------
__global__ __launch_bounds__(256) void k_prep(const float* __restrict__ xin,
                                              float* __restrict__ xm,
                                              unsigned short* __restrict__ kq,
                                              unsigned short* __restrict__ vv) {
    const int j = blockIdx.x * 256 + threadIdx.x;
    float xv[DIM];
#pragma unroll
    for (int d = 0; d < DIM; ++d) xv[d] = xin[(size_t)d * NPIX + j];

    float4* xmr = (float4*)(xm + (size_t)j * DIM);
#pragma unroll
    for (int q = 0; q < 8; ++q)
        xmr[q] = make_float4(xv[4*q], xv[4*q+1], xv[4*q+2], xv[4*q+3]);

    uint4* kq4 = (uint4*)kq;
#pragma unroll
    for (int ks = 0; ks < 2; ++ks)
#pragma unroll
        for (int h = 0; h < 2; ++h) {
            const int b = ks * 16 + h * 8;
            unsigned w0 = (unsigned)f2bf(xv[b+0]*ALPHA) | ((unsigned)f2bf(xv[b+1]*ALPHA) << 16);
            unsigned w1 = (unsigned)f2bf(xv[b+2]*ALPHA) | ((unsigned)f2bf(xv[b+3]*ALPHA) << 16);
            unsigned w2 = (unsigned)f2bf(xv[b+4]*ALPHA) | ((unsigned)f2bf(xv[b+5]*ALPHA) << 16);
            unsigned w3 = (unsigned)f2bf(xv[b+6]*ALPHA) | ((unsigned)f2bf(xv[b+7]*ALPHA) << 16);
            kq4[(j >> 5) * 128 + ks * 64 + h * 32 + (j & 31)] = make_uint4(w0, w1, w2, w3);
        }

    const int vbase = (j >> 5) * 1024 + ((j >> 4) & 1) * 512 + ((j >> 3) & 1) * 256 + (j & 7);
#pragma unroll
    for (int d = 0; d < DIM; ++d) vv[vbase + d * 8] = f2bf(xv[d]);
}

// ---------------- reduce + blend + regenerate, 4 threads per j ----------------
__global__ __launch_bounds__(256) void k_upd(const float* __restrict__ party,
                                             const float* __restrict__ partd,
                                             const float* __restrict__ xm,
                                             float* __restrict__ xm_next,
                                             unsigned short* __restrict__ kq,
                                             unsigned short* __restrict__ vv,
                                             float* __restrict__ out,
                                             int last) {
    const int t = blockIdx.x * 256 + threadIdx.x;   // 0..32767
    const int j = t >> 2, q = t & 3;                // q: which 8-dim slice

    float4 ya = make_float4(0.f, 0.f, 0.f, 0.f);
    float4 yb = make_float4(0.f, 0.f, 0.f, 0.f);
    float dg = 0.f;
    for (int c = 0; c < SCH; ++c) {
        const float4* p4 = (const float4*)(party + ((size_t)c * NPIX + j) * 32 + q * 8);
        float4 a = p4[0], b = p4[1];
        ya.x += a.x; ya.y += a.y; ya.z += a.z; ya.w += a.w;
        yb.x += b.x; yb.y += b.y; yb.z += b.z; yb.w += b.w;
        dg += partd[(size_t)c * NPIX + j];           // 4 threads share addr (L1 bcast)
    }
    const float inv = 0.5f / dg;

    const float4* xr = (const float4*)(xm + (size_t)j * DIM + q * 8);
    float4 v0 = xr[0], v1 = xr[1];
    float xn[8];
    xn[0] = fmaf(ya.x, inv, 0.5f * v0.x);
    xn[1] = fmaf(ya.y, inv, 0.5f * v0.y);
    xn[2] = fmaf(ya.z, inv, 0.5f * v0.z);
    xn[3] = fmaf(ya.w, inv, 0.5f * v0.w);
    xn[4] = fmaf(yb.x, inv, 0.5f * v1.x);
    xn[5] = fmaf(yb.y, inv, 0.5f * v1.y);
    xn[6] = fmaf(yb.z, inv, 0.5f * v1.z);
    xn[7] = fmaf(yb.w, inv, 0.5f * v1.w);

    if (last) {
#pragma unroll
        for (int e = 0; e < 8; ++e) out[(size_t)(q * 8 + e) * NPIX + j] = xn[e];
        return;
    }

    float4* xw = (float4*)(xm_next + (size_t)j * DIM + q * 8);
    xw[0] = make_float4(xn[0], xn[1], xn[2], xn[3]);
    xw[1] = make_float4(xn[4], xn[5], xn[6], xn[7]);

    unsigned w0 = (unsigned)f2bf(xn[0]*ALPHA) | ((unsigned)f2bf(xn[1]*ALPHA) << 16);
    unsigned w1 = (unsigned)f2bf(xn[2]*ALPHA) | ((unsigned)f2bf(xn[3]*ALPHA) << 16);
    unsigned w2 = (unsigned)f2bf(xn[4]*ALPHA) | ((unsigned)f2bf(xn[5]*ALPHA) << 16);
    unsigned w3 = (unsigned)f2bf(xn[6]*ALPHA) | ((unsigned)f2bf(xn[7]*ALPHA) << 16);
    ((uint4*)kq)[(j >> 5) * 128 + (q >> 1) * 64 + (q & 1) * 32 + (j & 31)] =
        make_uint4(w0, w1, w2, w3);

    const int vbase = (j >> 5) * 1024 + ((j >> 4) & 1) * 512 + ((j >> 3) & 1) * 256 + (j & 7);
#pragma unroll
    for (int e = 0; e < 8; ++e) vv[vbase + (q * 8 + e) * 8] = f2bf(xn[e]);
}

extern "C" void kernel_launch(void* const* d_in, const int* in_sizes, int n_in,
                              void* d_out, int out_size, void* d_ws, size_t ws_size,
                              hipStream_t stream) {
    const float* x_in = (const float*)d_in[0];
    float* out = (float*)d_out;

    const size_t nd = (size_t)NPIX * DIM;          // 262144
    float* xmA = (float*)d_ws;
    float* xmB = xmA + nd;
    float* party = xmB + nd;                       // SCH*8192*32 floats (16.8 MB)
    float* partd = party + (size_t)SCH * NPIX * 32;  // SCH*8192 floats
    unsigned short* kq = (unsigned short*)(partd + (size_t)SCH * NPIX);
    unsigned short* vv = kq + nd;

    k_prep<<<NPIX / 256, 256, 0, stream>>>(x_in, xmA, kq, vv);

    for (int it = 0; it < NITER; ++it) {
        const int last = (it == NITER - 1);
        k_ms<<<SCH * 64, 256, 0, stream>>>(kq, vv, party, partd);
        k_upd<<<(NPIX * 4) / 256, 256, 0, stream>>>(party, partd, xmA, xmB, kq, vv, out, last);
        float* t = xmA; xmA = xmB; xmB = t;
    }
}